// Round 21
// baseline (407.359 us; speedup 1.0000x reference)
//
#include <hip/hip_runtime.h>
#include <hip/hip_bf16.h>
#include <cstdint>
#include <cstddef>

typedef __bf16 bf16_t;
typedef __bf16 bf16x8 __attribute__((ext_vector_type(8)));
typedef float f32x4 __attribute__((ext_vector_type(4)));

#define GLD16(src, dst)                                                       \
    __builtin_amdgcn_global_load_lds(                                         \
        (const __attribute__((address_space(1))) void*)(src),                 \
        (__attribute__((address_space(3))) void*)(dst), 16, 0, 0)

// s_barrier WITH compiler memory fence (R8 lesson).
#define BAR() asm volatile("s_barrier" ::: "memory")
#define LGKM0() asm volatile("s_waitcnt lgkmcnt(0)" ::: "memory")

// ---------------------------------------------------------------------------
// Build Mt[n][k] (bf16, [N][K]) from the quaternion Hamilton block structure.
// ---------------------------------------------------------------------------
__global__ __launch_bounds__(256) void pack_w_kernel(const float* __restrict__ Wa,
                                                     const float* __restrict__ Wb,
                                                     const float* __restrict__ Wc,
                                                     const float* __restrict__ Wd,
                                                     bf16_t* __restrict__ Mt) {
    __shared__ float tile[64][65];
    const int kb = blockIdx.x * 64;
    const int nb = blockIdx.y * 64;
    const int i = kb >> 10;
    const int j = nb >> 10;

    const float* W[4] = {Wa, Wb, Wc, Wd};
    const int srcIdx[4][4] = {{0, 1, 2, 3}, {1, 0, 3, 2}, {2, 3, 0, 1}, {3, 2, 1, 0}};
    const float sgn[4][4] = {{1.f, 1.f, 1.f, 1.f},
                             {-1.f, 1.f, -1.f, 1.f},
                             {-1.f, 1.f, 1.f, -1.f},
                             {-1.f, -1.f, 1.f, 1.f}};
    const float* Ws = W[srcIdx[i][j]];
    const float s = sgn[i][j];

    const int kq = kb & 1023;
    const int nq = nb & 1023;
    const int tx = threadIdx.x & 63;
    const int ty = threadIdx.x >> 6;

    for (int r = ty; r < 64; r += 4)
        tile[r][tx] = Ws[(size_t)(kq + r) * 1024 + (nq + tx)];
    __syncthreads();
    for (int r = ty; r < 64; r += 4)
        Mt[(size_t)(nb + r) * 4096 + (kb + tx)] = (bf16_t)(s * tile[tx][r]);
}

// ---------------------------------------------------------------------------
// 256x256 GEMM, FUSED fp32->bf16 A-conversion (no separate cvt pass).
// R20 protocol (4 barriers/tile, unrolled x2, c-outer mmac, decoupled reads),
// with A staged by REGISTERS: f32 global loads issued >=2 phases early ->
// cvt -> ds_write_b128 at the old stage point (LDS image byte-identical to
// the old GLD16 layout, so read swizzle unchanged).
//
// Sync ledger (re-derived; B = GLD16, A = ds_write):
//  * Each writeA's cvt carries a compiler vmcnt wait on its f32 loads, which
//    FIFO-drains ALL older VMEM -- including every B GLD16 issued before
//    those f32 loads.  This replaces the explicit VM4:
//      b1(t)@p0(t):  Bh1(t)@p2(t-2) < LA1(t)@p3(t-2) -> drained by the
//        cvt@p0(t-1) + BAR(p0,t-1).
//      b0(t+1)@p3(t): Bh0(t+1)@p1(t-1) < LA0(t+1)@p1(t-1) -> drained by
//        cvt@p3(t-1) + BAR(p3,t-1).
//  * A visibility: writeA + LGKM0 before the phase-end BAR; readers are >=1
//    (usually 3-4) barriers later.  a_mh0(t+1)@p3(t) reads Ah0(t+1)
//    [written p3(t-1)] for wr=0 and Ah1(t+1) [written p0(t)] for wr=1 ✓.
//  * WAR: writeA Ah0(t+2)@p3(t) vs a(t) reads [complete < BAR(p2,t)] ✓;
//    writeA Ah1(t+2)@p0(t+1) -> idle buf ✓; B stages as in R20 ✓.
//  * VMEM issue order/tile: p1: B0(t+2),LA0(t+2); p2: B1(t+2); p3: LA1(t+2).
//    f32 loads -> cvt gap = 2 barrier intervals (~2000 cy > 900 cy HBM).
//  * Tails: guards tt+1/tt+2 as R20; last cvt@p0(NT-2) drains B(NT-1).
// Registers: acc 128 + a 16 + b 16 + rA0/rA1 32 + addr ~= 215 < 256.
// ---------------------------------------------------------------------------
__global__ __launch_bounds__(512, 2) void qgemm_kernel(const float* __restrict__ X,
                                                       const bf16_t* __restrict__ Bt,
                                                       const float* __restrict__ bias,
                                                       float* __restrict__ C) {
    constexpr int N = 4096, K = 4096;
    constexpr int NT = K / 64;
    extern __shared__ __align__(16) char lds[];

    const int tid = threadIdx.x;
    const int w = tid >> 6;
    const int lane = tid & 63;
    const int l15 = lane & 15, l4 = lane >> 4;
    const int wr = w >> 2, wc = w & 3;  // 2 x 4 wave grid

    // XCD-aware swizzle (512 = 8*64, bijective)
    const int wg = blockIdx.x;
    const int swz = (wg & 7) * 64 + (wg >> 3);
    const int brow = (swz >> 4) * 256;  // 32 tile rows
    const int bcol = (swz & 15) * 256;  // 16 tile cols

    // staging: LDS stores k-block' = kb ^ (row&7); source k permuted per lane
    const int srow = lane >> 3;
    const int skb = (lane & 7) ^ (lane >> 3);

    // B staging unchanged: GLD16, linear dest
    auto stageB = [&](int buf, int h, int tt) {
#pragma unroll
        for (int q = 0; q < 2; ++q) {
            const bf16_t* src = Bt + (size_t)(bcol + h * 128 + w * 16 + q * 8 + srow) * K +
                                tt * 64 + skb * 8;
            GLD16(src, lds + 65536 + buf * 32768 + h * 16384 + w * 2048 + q * 1024);
        }
    };

    f32x4 rA0[4], rA1[4];  // in-flight f32 A data (issue-early / write-late)

    // issue 4 dwordx4 of f32 x for A-half h of tile tt
    auto loadAf = [&](int h, int tt, f32x4(&r)[4]) {
#pragma unroll
        for (int q = 0; q < 2; ++q) {
            const float* src = X + (size_t)(brow + h * 128 + w * 16 + q * 8 + srow) * K +
                               tt * 64 + skb * 8;
            r[q * 2 + 0] = *(const f32x4*)(src);
            r[q * 2 + 1] = *(const f32x4*)(src + 4);
        }
    };
    // cvt + ds_write (image identical to old GLD16 dest: linear lane*16)
    auto writeA = [&](int buf, int h, f32x4(&r)[4]) {
#pragma unroll
        for (int q = 0; q < 2; ++q) {
            bf16x8 o;
#pragma unroll
            for (int j = 0; j < 4; ++j) {
                o[j] = (bf16_t)r[q * 2 + 0][j];
                o[4 + j] = (bf16_t)r[q * 2 + 1][j];
            }
            *(bf16x8*)(lds + buf * 32768 + h * 16384 + w * 2048 + q * 1024 + lane * 16) = o;
        }
    };

    f32x4 acc[8][4] = {};
    bf16x8 a[4][2], b0[2][2], b1[2][2];

    auto ldAm = [&](int buf, int mh, int m) {
#pragma unroll
        for (int c = 0; c < 2; ++c)
            a[m][c] = *(const bf16x8*)(lds + buf * 32768 + wr * 16384 +
                                       (mh * 64 + m * 16 + l15) * 128 +
                                       ((c * 4 + l4) ^ (l15 & 7)) * 16);
    };
    auto ldB = [&](int buf, int nh, bf16x8(&b)[2][2]) {
#pragma unroll
        for (int n = 0; n < 2; ++n)
#pragma unroll
            for (int c = 0; c < 2; ++c)
                b[n][c] = *(const bf16x8*)(lds + 65536 + buf * 32768 + nh * 16384 +
                                           (wc * 32 + n * 16 + l15) * 128 +
                                           ((c * 4 + l4) ^ (l15 & 7)) * 16);
    };
    auto mmac = [&](int mh, int nh, bf16x8(&b)[2][2]) {
        __builtin_amdgcn_s_setprio(1);
#pragma unroll
        for (int c = 0; c < 2; ++c)
#pragma unroll
            for (int m = 0; m < 4; ++m)
#pragma unroll
                for (int n = 0; n < 2; ++n)
                    acc[mh * 4 + m][nh * 2 + n] = __builtin_amdgcn_mfma_f32_16x16x32_bf16(
                        a[m][c], b[n][c], acc[mh * 4 + m][nh * 2 + n], 0, 0, 0);
        __builtin_amdgcn_s_setprio(0);
    };

#define TILE_BODY(CUR, TT)                                                    \
    {                                                                         \
        const int tt = (TT);                                                  \
        /* p0: writeA Ah1(t+1) -> idle buf; read b1(t); mmac00 */             \
        if (tt + 1 < NT) {                                                    \
            writeA((CUR) ^ 1, 1, rA1);                                        \
            LGKM0();                                                          \
        }                                                                     \
        ldB((CUR), 1, b1);                                                    \
        mmac(0, 0, b0);                                                       \
        BAR();                                                                \
        /* p1: stage Bh0(t+2) + issue f32 LA0(t+2); mmac01; read a(mh1) */    \
        if (tt + 2 < NT) {                                                    \
            stageB((CUR), 0, tt + 2);                                         \
            loadAf(0, tt + 2, rA0);                                           \
        }                                                                     \
        mmac(0, 1, b1);                                                       \
        ldAm((CUR), 1, 0);                                                    \
        ldAm((CUR), 1, 1);                                                    \
        ldAm((CUR), 1, 2);                                                    \
        ldAm((CUR), 1, 3);                                                    \
        BAR();                                                                \
        /* p2: stage Bh1(t+2); mmac11 */                                      \
        if (tt + 2 < NT) stageB((CUR), 1, tt + 2);                            \
        mmac(1, 1, b1);                                                       \
        BAR();                                                                \
        /* p3: writeA Ah0(t+2) -> live buf (cvt drains all of t+1's VMEM);    \
           issue f32 LA1(t+2); mmac10; preload b0,a_mh0 of t+1 */             \
        if (tt + 2 < NT) {                                                    \
            writeA((CUR), 0, rA0);                                            \
            LGKM0();                                                          \
            loadAf(1, tt + 2, rA1);                                           \
        }                                                                     \
        mmac(1, 0, b0);                                                       \
        if (tt + 1 < NT) {                                                    \
            ldB((CUR) ^ 1, 0, b0);                                            \
            ldAm((CUR) ^ 1, 0, 0);                                            \
            ldAm((CUR) ^ 1, 0, 1);                                            \
            ldAm((CUR) ^ 1, 0, 2);                                            \
            ldAm((CUR) ^ 1, 0, 3);                                            \
        }                                                                     \
        BAR();                                                                \
    }

    // prologue: B(0),B(1) staged; A(0) loaded+written; Ah0(1) written;
    // LA1(1) left in rA1 for p0(0).  cvt waits drain B(0)/B(1) in order.
    stageB(0, 0, 0);
    stageB(0, 1, 0);
    loadAf(0, 0, rA0);
    loadAf(1, 0, rA1);
    stageB(1, 0, 1);
    stageB(1, 1, 1);
    writeA(0, 0, rA0);  // waits LA_h0(0) -> drains B(0)
    writeA(0, 1, rA1);  // waits LA_h1(0)
    loadAf(0, 1, rA0);  // LA0(1)
    writeA(1, 0, rA0);  // Ah0(1): waits LA0(1) -> drains B(1)
    loadAf(1, 1, rA1);  // LA1(1), consumed at p0(0)
    LGKM0();
    BAR();
    ldB(0, 0, b0);
    ldAm(0, 0, 0);
    ldAm(0, 0, 1);
    ldAm(0, 0, 2);
    ldAm(0, 0, 3);

    for (int it = 0; it < NT / 2; ++it) {
        TILE_BODY(0, 2 * it);
        TILE_BODY(1, 2 * it + 1);
    }
#undef TILE_BODY

    // epilogue: C/D layout col = lane&15, row = (lane>>4)*4 + i.
    // B mapping: global n -> col = (n>>1)*128 + wc*32 + (n&1)*16
#pragma unroll
    for (int n = 0; n < 4; ++n) {
        const int col = bcol + (n >> 1) * 128 + wc * 32 + (n & 1) * 16 + l15;
        const float bv = bias[col];
#pragma unroll
        for (int m = 0; m < 8; ++m) {
            const int row0 = brow + wr * 128 + m * 16 + l4 * 4;
            const f32x4 v = acc[m][n];
#pragma unroll
            for (int i = 0; i < 4; ++i)
                C[(size_t)(row0 + i) * N + col] = v[i] + bv;
        }
    }
}

// ---------------------------------------------------------------------------
extern "C" void kernel_launch(void* const* d_in, const int* in_sizes, int n_in,
                              void* d_out, int out_size, void* d_ws, size_t ws_size,
                              hipStream_t stream) {
    const float* x = (const float*)d_in[0];
    const float* Wa = (const float*)d_in[1];
    const float* Wb = (const float*)d_in[2];
    const float* Wc = (const float*)d_in[3];
    const float* Wd = (const float*)d_in[4];
    const float* bias = (const float*)d_in[5];
    float* out = (float*)d_out;

    const int M = 8192, N = 4096;

    bf16_t* Mt = (bf16_t*)d_ws;  // [N][K] bf16 packed Hamilton matrix

    pack_w_kernel<<<dim3(64, 64), 256, 0, stream>>>(Wa, Wb, Wc, Wd, Mt);

    (void)hipFuncSetAttribute((const void*)qgemm_kernel,
                              hipFuncAttributeMaxDynamicSharedMemorySize, 131072);
    qgemm_kernel<<<dim3((M / 256) * (N / 256)), 512, 131072, stream>>>(x, Mt, bias, out);
}

// Round 22
// 271.643 us; speedup vs baseline: 1.4996x; 1.4996x over previous
//
#include <hip/hip_runtime.h>
#include <hip/hip_bf16.h>
#include <cstdint>
#include <cstddef>

typedef __bf16 bf16_t;
typedef __bf16 bf16x4 __attribute__((ext_vector_type(4)));
typedef __bf16 bf16x8 __attribute__((ext_vector_type(8)));
typedef float f32x4 __attribute__((ext_vector_type(4)));

#define GLD16(src, dst)                                                       \
    __builtin_amdgcn_global_load_lds(                                         \
        (const __attribute__((address_space(1))) void*)(src),                 \
        (__attribute__((address_space(3))) void*)(dst), 16, 0, 0)

// s_barrier WITH compiler memory fence (R8 lesson).
#define BAR() asm volatile("s_barrier" ::: "memory")
#define WAIT_VM4() asm volatile("s_waitcnt vmcnt(4)" ::: "memory")
#define WAIT_VM6() asm volatile("s_waitcnt vmcnt(6)" ::: "memory")
#define WAIT_VM0() asm volatile("s_waitcnt vmcnt(0)" ::: "memory")

// ---------------------------------------------------------------------------
// Fused prep: blocks [0,4096) convert x fp32->bf16 (grid-stride, vectorized);
// blocks [4096,8192) pack Mt[n][k] from the Hamilton block structure.
// Independent work partitions; both HBM-bound, so pack rides under cvt's
// stream instead of serializing behind it (saves a launch + pack's tail).
// ---------------------------------------------------------------------------
__global__ __launch_bounds__(256) void prep_kernel(const float* __restrict__ x,
                                                   bf16_t* __restrict__ xb,
                                                   const float* __restrict__ Wa,
                                                   const float* __restrict__ Wb,
                                                   const float* __restrict__ Wc,
                                                   const float* __restrict__ Wd,
                                                   bf16_t* __restrict__ Mt) {
    const int bid = blockIdx.x;
    if (bid < 4096) {
        // ---- cvt part: x [8192][4096] fp32 -> xb bf16 ----
        constexpr int n4 = (8192 * 4096) / 4;
        int idx = bid * 256 + threadIdx.x;
        constexpr int stride = 4096 * 256;
        const f32x4* xv = (const f32x4*)x;
        bf16x4* ov = (bf16x4*)xb;
        for (int i = idx; i < n4; i += stride) {
            f32x4 v = xv[i];
            bf16x4 o;
            o[0] = (bf16_t)v[0];
            o[1] = (bf16_t)v[1];
            o[2] = (bf16_t)v[2];
            o[3] = (bf16_t)v[3];
            ov[i] = o;
        }
    } else {
        // ---- pack part: one 64x64 tile of Mt per block ----
        __shared__ float tile[64][65];
        const int pb = bid - 4096;
        const int kb = (pb & 63) * 64;
        const int nb = (pb >> 6) * 64;
        const int i = kb >> 10;
        const int j = nb >> 10;

        const float* W[4] = {Wa, Wb, Wc, Wd};
        const int srcIdx[4][4] = {{0, 1, 2, 3}, {1, 0, 3, 2}, {2, 3, 0, 1}, {3, 2, 1, 0}};
        const float sgn[4][4] = {{1.f, 1.f, 1.f, 1.f},
                                 {-1.f, 1.f, -1.f, 1.f},
                                 {-1.f, 1.f, 1.f, -1.f},
                                 {-1.f, -1.f, 1.f, 1.f}};
        const float* Ws = W[srcIdx[i][j]];
        const float s = sgn[i][j];

        const int kq = kb & 1023;
        const int nq = nb & 1023;
        const int tx = threadIdx.x & 63;
        const int ty = threadIdx.x >> 6;

        for (int r = ty; r < 64; r += 4)
            tile[r][tx] = Ws[(size_t)(kq + r) * 1024 + (nq + tx)];
        __syncthreads();
        for (int r = ty; r < 64; r += 4)
            Mt[(size_t)(nb + r) * 4096 + (kb + tx)] = (bf16_t)(s * tile[tx][r]);
    }
}

// ---------------------------------------------------------------------------
// 256x256 GEMM — R20 (best passing): 4 barriers/tile, unrolled x2, c-outer
// mmac, decoupled reads, read/MFMA interleave in p1/p3, T2 swizzle, XCD
// swizzle, GLD16 staging, VM4@p2 counted drain.
//   p0: stageAh1(t+1,IDLE); ldB b1(t); mmac00                          |BAR|
//   p1: stageBh0(t+2); [8xMFMA|ldAm mh1 m0,m1|8xMFMA|ldAm m2,m3]       |BAR|
//   p2: stageBh1(t+2); mmac11; VM4(/VM0)                               |BAR|
//   p3: stageAh0(t+2); [8xMFMA|pre a m0,m1|8xMFMA|pre a m2,m3, b0]     |BAR|
// Ledger as audited R18/R19 (issuer-drain + common-barrier everywhere).
// ---------------------------------------------------------------------------
__global__ __launch_bounds__(512, 2) void qgemm_kernel(const bf16_t* __restrict__ A,
                                                       const bf16_t* __restrict__ Bt,
                                                       const float* __restrict__ bias,
                                                       float* __restrict__ C) {
    constexpr int N = 4096, K = 4096;
    constexpr int NT = K / 64;
    extern __shared__ __align__(16) char lds[];

    const int tid = threadIdx.x;
    const int w = tid >> 6;
    const int lane = tid & 63;
    const int l15 = lane & 15, l4 = lane >> 4;
    const int wr = w >> 2, wc = w & 3;  // 2 x 4 wave grid

    // XCD-aware swizzle (512 = 8*64, bijective)
    const int wg = blockIdx.x;
    const int swz = (wg & 7) * 64 + (wg >> 3);
    const int brow = (swz >> 4) * 256;  // 32 tile rows
    const int bcol = (swz & 15) * 256;  // 16 tile cols

    // staging: LDS stores k-block' = kb ^ (row&7); dest linear, global source
    // k-block for lane slot (lane&7) at row (lane>>3) is the inverse perm:
    const int srow = lane >> 3;
    const int skb = (lane & 7) ^ (lane >> 3);

    auto stageA = [&](int buf, int h, int tt) {
#pragma unroll
        for (int q = 0; q < 2; ++q) {
            const bf16_t* src = A + (size_t)(brow + h * 128 + w * 16 + q * 8 + srow) * K +
                                tt * 64 + skb * 8;
            GLD16(src, lds + buf * 32768 + h * 16384 + w * 2048 + q * 1024);
        }
    };
    auto stageB = [&](int buf, int h, int tt) {
#pragma unroll
        for (int q = 0; q < 2; ++q) {
            const bf16_t* src = Bt + (size_t)(bcol + h * 128 + w * 16 + q * 8 + srow) * K +
                                tt * 64 + skb * 8;
            GLD16(src, lds + 65536 + buf * 32768 + h * 16384 + w * 2048 + q * 1024);
        }
    };

    f32x4 acc[8][4] = {};
    bf16x8 a[4][2], b0[2][2], b1[2][2];

    // one A m-frag (2 reads): row = wr-half, mh sub-half, frag m
    auto ldAm = [&](int buf, int mh, int m) {
#pragma unroll
        for (int c = 0; c < 2; ++c)
            a[m][c] = *(const bf16x8*)(lds + buf * 32768 + wr * 16384 +
                                       (mh * 64 + m * 16 + l15) * 128 +
                                       ((c * 4 + l4) ^ (l15 & 7)) * 16);
    };
    // B frags: nh selects the STAGING half; wave cols = nh*128 + wc*32 + n*16
    auto ldB = [&](int buf, int nh, bf16x8(&b)[2][2]) {
#pragma unroll
        for (int n = 0; n < 2; ++n)
#pragma unroll
            for (int c = 0; c < 2; ++c)
                b[n][c] = *(const bf16x8*)(lds + 65536 + buf * 32768 + nh * 16384 +
                                           (wc * 32 + n * 16 + l15) * 128 +
                                           ((c * 4 + l4) ^ (l15 & 7)) * 16);
    };
    // full 16-MFMA cluster (c outermost: 8 independent between acc reuses)
    auto mmac = [&](int mh, int nh, bf16x8(&b)[2][2]) {
        __builtin_amdgcn_s_setprio(1);
#pragma unroll
        for (int c = 0; c < 2; ++c)
#pragma unroll
            for (int m = 0; m < 4; ++m)
#pragma unroll
                for (int n = 0; n < 2; ++n)
                    acc[mh * 4 + m][nh * 2 + n] = __builtin_amdgcn_mfma_f32_16x16x32_bf16(
                        a[m][c], b[n][c], acc[mh * 4 + m][nh * 2 + n], 0, 0, 0);
        __builtin_amdgcn_s_setprio(0);
    };
    // 8-MFMA pair cluster: m in {2*mp, 2*mp+1}; c outer -> dep distance 4
    auto mmac_pair = [&](int mh, int nh, int mp, bf16x8(&b)[2][2]) {
        __builtin_amdgcn_s_setprio(1);
#pragma unroll
        for (int c = 0; c < 2; ++c)
#pragma unroll
            for (int m2 = 0; m2 < 2; ++m2)
#pragma unroll
                for (int n = 0; n < 2; ++n) {
                    const int m = mp * 2 + m2;
                    acc[mh * 4 + m][nh * 2 + n] = __builtin_amdgcn_mfma_f32_16x16x32_bf16(
                        a[m][c], b[n][c], acc[mh * 4 + m][nh * 2 + n], 0, 0, 0);
                }
        __builtin_amdgcn_s_setprio(0);
    };

// One K-tile, LITERAL buffer index CUR, ONE barrier per phase, p1/p3
// read-issues chained into the MFMA stream via reg-WAR.
#define TILE_BODY(CUR, TT)                                                    \
    {                                                                         \
        const int tt = (TT);                                                  \
        /* p0: consume a(mh0),b0; read b1(t) ahead of mmac00 */               \
        if (tt + 1 < NT) stageA((CUR) ^ 1, 1, tt + 1);                        \
        ldB((CUR), 1, b1);                                                    \
        mmac(0, 0, b0);                                                       \
        BAR();                                                                \
        /* p1: consume a(mh0),b1; reload a with mh1 interleaved per-pair */   \
        if (tt + 2 < NT) stageB((CUR), 0, tt + 2);                            \
        mmac_pair(0, 1, 0, b1);                                               \
        ldAm((CUR), 1, 0);                                                    \
        ldAm((CUR), 1, 1);                                                    \
        mmac_pair(0, 1, 1, b1);                                               \
        ldAm((CUR), 1, 2);                                                    \
        ldAm((CUR), 1, 3);                                                    \
        BAR();                                                                \
        /* p2: consume a(mh1),b1; counted drain BEFORE the barrier */         \
        if (tt + 2 < NT) stageB((CUR), 1, tt + 2);                            \
        mmac(1, 1, b1);                                                       \
        if (tt + 2 < NT) {                                                    \
            WAIT_VM4();                                                       \
        } else {                                                              \
            WAIT_VM0();                                                       \
        }                                                                     \
        BAR();                                                                \
        /* p3: consume a(mh1),b0; preload t+1 interleaved per-pair */         \
        if (tt + 2 < NT) stageA((CUR), 0, tt + 2);                            \
        mmac_pair(1, 0, 0, b0);                                               \
        if (tt + 1 < NT) {                                                    \
            ldAm((CUR) ^ 1, 0, 0);                                            \
            ldAm((CUR) ^ 1, 0, 1);                                            \
        }                                                                     \
        mmac_pair(1, 0, 1, b0);                                               \
        if (tt + 1 < NT) {                                                    \
            ldAm((CUR) ^ 1, 0, 2);                                            \
            ldAm((CUR) ^ 1, 0, 3);                                            \
            ldB((CUR) ^ 1, 0, b0);                                            \
        }                                                                     \
        BAR();                                                                \
    }

    // prologue: tile0 full (8 loads, buf0) + tile1's Bh0/Bh1/Ah0 (6, buf1);
    // VM6 drains tile0 (issuer drain), BAR (common), preload b0 + full a_mh0.
    stageA(0, 0, 0);
    stageA(0, 1, 0);
    stageB(0, 0, 0);
    stageB(0, 1, 0);
    stageB(1, 0, 1);
    stageB(1, 1, 1);
    stageA(1, 0, 1);
    WAIT_VM6();
    BAR();
    ldB(0, 0, b0);
    ldAm(0, 0, 0);
    ldAm(0, 0, 1);
    ldAm(0, 0, 2);
    ldAm(0, 0, 3);

    // main loop: 2 K-tiles per iteration, buf indices compile-time 0/1
    for (int it = 0; it < NT / 2; ++it) {
        TILE_BODY(0, 2 * it);
        TILE_BODY(1, 2 * it + 1);
    }
#undef TILE_BODY

    // epilogue: C/D layout col = lane&15, row = (lane>>4)*4 + i.
    // B mapping: global n -> col = (n>>1)*128 + wc*32 + (n&1)*16
#pragma unroll
    for (int n = 0; n < 4; ++n) {
        const int col = bcol + (n >> 1) * 128 + wc * 32 + (n & 1) * 16 + l15;
        const float bv = bias[col];
#pragma unroll
        for (int m = 0; m < 8; ++m) {
            const int row0 = brow + wr * 128 + m * 16 + l4 * 4;
            const f32x4 v = acc[m][n];
#pragma unroll
            for (int i = 0; i < 4; ++i)
                C[(size_t)(row0 + i) * N + col] = v[i] + bv;
        }
    }
}

// ---------------------------------------------------------------------------
extern "C" void kernel_launch(void* const* d_in, const int* in_sizes, int n_in,
                              void* d_out, int out_size, void* d_ws, size_t ws_size,
                              hipStream_t stream) {
    const float* x = (const float*)d_in[0];
    const float* Wa = (const float*)d_in[1];
    const float* Wb = (const float*)d_in[2];
    const float* Wc = (const float*)d_in[3];
    const float* Wd = (const float*)d_in[4];
    const float* bias = (const float*)d_in[5];
    float* out = (float*)d_out;

    const int M = 8192, N = 4096, K = 4096;

    bf16_t* xb = (bf16_t*)d_ws;       // [M][K] bf16
    bf16_t* Mt = xb + (size_t)M * K;  // [N][K] bf16

    prep_kernel<<<8192, 256, 0, stream>>>(x, xb, Wa, Wb, Wc, Wd, Mt);

    (void)hipFuncSetAttribute((const void*)qgemm_kernel,
                              hipFuncAttributeMaxDynamicSharedMemorySize, 131072);
    qgemm_kernel<<<dim3((M / 256) * (N / 256)), 512, 131072, stream>>>(xb, Mt, bias, out);
}